// Round 2
// baseline (15691.145 us; speedup 1.0000x reference)
//
#include <hip/hip_runtime.h>

// LSTM surrogate: B=256, T=512, D=256, U=512, O=64.
// 8 batch-groups x 32 unit-groups = 256 blocks (1/CU), PLAIN launch (round-1
// failure diagnosed as silent hipLaunchCooperativeKernel failure -> all-zero out).
// Co-residency of the 32 blocks per batch-group is guaranteed by capacity:
// 256 blocks / 256 CUs, each CU can host >=2 such blocks (59.6KB LDS, <=256 VGPR).
// Per block: 32 batch rows, 16 units (64 gate cols). Weights as MFMA B-frags in
// registers; z=[x_t|h] staged in XOR-swizzled LDS; per-group 32-block barrier.

#define Bb 256
#define Tt 512
#define Dd 256
#define Uu 512
#define Oo 64

typedef short bs8 __attribute__((ext_vector_type(8)));      // 8 bf16 (bits)
typedef float f32x16 __attribute__((ext_vector_type(16)));

__device__ __forceinline__ unsigned short f2bf(float f) {
  unsigned u = __float_as_uint(f);
  u += 0x7fffu + ((u >> 16) & 1u);                          // RNE
  return (unsigned short)(u >> 16);
}
__device__ __forceinline__ float bf2f(unsigned short s) {
  return __uint_as_float(((unsigned)s) << 16);
}
__device__ __forceinline__ float sigm(float v) { return 1.0f / (1.0f + __expf(-v)); }
__device__ __forceinline__ float tanhfast(float v) { return 2.0f / (1.0f + __expf(-2.0f * v)) - 1.0f; }

// z LDS: [32 rows][768 k] bf16, row stride 1536 B. XOR swizzle on 16B granules
// breaks the 32-way bank conflict of the stride-1536 column read (G4 / m214).
// Bijective: row ranges are 512-aligned, XOR touches only bits 4..6.
__device__ __forceinline__ int zbyte(int row, int k) {
  return (row * 1536 + k * 2) ^ ((row & 7) << 4);
}

__global__ void rnn_init_bar(unsigned* bar) {
  int i = threadIdx.x;
  if (i < 256) bar[i] = 0u;
}

__launch_bounds__(256, 1)
__global__ void rnn_lstm_kernel(const float* __restrict__ x, const float* __restrict__ Wx,
                                const float* __restrict__ Wh, const float* __restrict__ bias,
                                const float* __restrict__ Wd, const float* __restrict__ bd,
                                float* __restrict__ out, unsigned short* hbuf, unsigned* bar) {
  __shared__ __align__(16) char zs[32 * 768 * 2];   // 49152 B
  __shared__ float cpT[2][32][33];                  // partial C, [nt][col][row], +1 pad
  __shared__ float ypart[32][2][8];                 // y partial sums

  const int tid = threadIdx.x;
  const int lane = tid & 63;
  const int wid = tid >> 6;
  const int bid = blockIdx.x;
  const int bg = bid & 7;        // batch group 0..7  (XCD-affine heuristic)
  const int ug = bid >> 3;       // unit group 0..31
  const int b_base = bg * 32;
  const int u_base = ug * 16;
  const int oc0 = ug * 2;
  const int kh = wid >> 1;       // K-half (0: k 0..383, 1: k 384..767)
  const int nt = wid & 1;        // N-tile (32 gate cols each)

  unsigned* cnt = bar + bg * 32;
  unsigned* gen = bar + bg * 32 + 16;

  // ---- load weight slice as B-fragments (once) ----
  // B-frag layout (32x32x16): col = lane&31, k = (lane>>5)*8 + e
  bs8 breg[24];
  {
    const int col = nt * 32 + (lane & 31);
    const int gate = col >> 4;                       // 0:i 1:f 2:g 3:o
    const int gc = gate * 512 + u_base + (col & 15); // global gate column
    const int kfr = (lane >> 5) * 8;
#pragma unroll
    for (int ks = 0; ks < 24; ++ks) {
      bs8 bb;
#pragma unroll
      for (int e = 0; e < 8; ++e) {
        int kg = kh * 384 + ks * 16 + kfr + e;
        float w = (kg < 256) ? Wx[(size_t)kg * 2048 + gc]
                             : Wh[(size_t)(kg - 256) * 2048 + gc];
        bb[e] = (short)f2bf(w);
      }
      breg[ks] = bb;
    }
  }

  // pointwise ownership: thread -> (prow = tid&31, usec = tid>>5), units usec*2+{0,1}
  const int prow = tid & 31;
  const int usec = tid >> 5;
  float bi[2], bff[2], bgg[2], boo[2];
#pragma unroll
  for (int j = 0; j < 2; ++j) {
    int ugl = u_base + usec * 2 + j;
    bi[j]  = bias[0 * 512 + ugl];
    bff[j] = bias[1 * 512 + ugl];
    bgg[j] = bias[2 * 512 + ugl];
    boo[j] = bias[3 * 512 + ugl];
  }
  float cst[2] = {0.f, 0.f};

  union U16 { unsigned long long q[2]; bs8 v; };

  for (int t = 0; t < Tt; ++t) {
    // ---- stage x_t into z[:, 0:256] ----
#pragma unroll
    for (int i = 0; i < 4; ++i) {
      int c = tid + i * 256;
      int row = c >> 5;
      int d0 = (c & 31) * 8;
      const float* xp = x + ((size_t)(b_base + row) * Tt + t) * Dd + d0;
      float4 v0 = *(const float4*)xp;
      float4 v1 = *(const float4*)(xp + 4);
      bs8 pk;
      pk[0] = (short)f2bf(v0.x); pk[1] = (short)f2bf(v0.y);
      pk[2] = (short)f2bf(v0.z); pk[3] = (short)f2bf(v0.w);
      pk[4] = (short)f2bf(v1.x); pk[5] = (short)f2bf(v1.y);
      pk[6] = (short)f2bf(v1.z); pk[7] = (short)f2bf(v1.w);
      *(bs8*)(zs + zbyte(row, d0)) = pk;
    }
    // ---- stage h_{t-1} into z[:, 256:768] (agent-scope loads: cross-XCD coherent) ----
    if (t == 0) {
#pragma unroll
      for (int i = 0; i < 8; ++i) {
        int c = tid + i * 256;
        int row = c >> 6;
        int u0 = (c & 63) * 8;
        bs8 zz = {0, 0, 0, 0, 0, 0, 0, 0};
        *(bs8*)(zs + zbyte(row, 256 + u0)) = zz;
      }
    } else {
      const unsigned short* hsrc = hbuf + (size_t)((t - 1) & 1) * Bb * Uu;
#pragma unroll
      for (int i = 0; i < 8; ++i) {
        int c = tid + i * 256;
        int row = c >> 6;
        int u0 = (c & 63) * 8;
        const unsigned long long* p =
            (const unsigned long long*)(hsrc + (size_t)(b_base + row) * Uu + u0);
        U16 uu;
        uu.q[0] = __hip_atomic_load(p, __ATOMIC_RELAXED, __HIP_MEMORY_SCOPE_AGENT);
        uu.q[1] = __hip_atomic_load(p + 1, __ATOMIC_RELAXED, __HIP_MEMORY_SCOPE_AGENT);
        *(bs8*)(zs + zbyte(row, 256 + u0)) = uu.v;
      }
    }
    __syncthreads();

    // ---- gates MFMA: C[32 rows x 32 cols] per (kh, nt) wave ----
    f32x16 acc = {0, 0, 0, 0, 0, 0, 0, 0, 0, 0, 0, 0, 0, 0, 0, 0};
    {
      const int arow = lane & 31;
      const int akf = (lane >> 5) * 8;
#pragma unroll
      for (int ks = 0; ks < 24; ++ks) {
        int k = kh * 384 + ks * 16 + akf;
        bs8 av = *(const bs8*)(zs + zbyte(arow, k));
        acc = __builtin_amdgcn_mfma_f32_32x32x16_bf16(av, breg[ks], acc, 0, 0, 0);
      }
    }
    // ---- K-split combine: kh=1 writes partials, kh=0 adds ----
    // C/D layout (HW-verified): col = lane&31, row = (reg&3) + 8*(reg>>2) + 4*(lane>>5)
    {
      const int col = lane & 31;
      const int rb = 4 * (lane >> 5);
      if (kh == 1) {
#pragma unroll
        for (int q = 0; q < 4; ++q)
#pragma unroll
          for (int j = 0; j < 4; ++j)
            cpT[nt][col][8 * q + rb + j] = acc[4 * q + j];
      }
      __syncthreads();
      if (kh == 0) {
#pragma unroll
        for (int q = 0; q < 4; ++q)
#pragma unroll
          for (int j = 0; j < 4; ++j)
            cpT[nt][col][8 * q + rb + j] += acc[4 * q + j];
      }
      __syncthreads();
    }

    // ---- pointwise LSTM cell; h published bf16 at agent scope ----
    {
      unsigned hpack = 0;
#pragma unroll
      for (int j = 0; j < 2; ++j) {
        int u = usec * 2 + j;
        float gi = cpT[0][u][prow]      + bi[j];
        float gf = cpT[0][16 + u][prow] + bff[j];
        float gg = cpT[1][u][prow]      + bgg[j];
        float go = cpT[1][16 + u][prow] + boo[j];
        float iv = sigm(gi), fv = sigm(gf), gv = tanhfast(gg), ov = sigm(go);
        float cn = fv * cst[j] + iv * gv;
        cst[j] = cn;
        float hv = ov * tanhfast(cn);
        hpack |= ((unsigned)f2bf(hv)) << (16 * j);
      }
      unsigned* hp = (unsigned*)(hbuf + (size_t)(t & 1) * Bb * Uu +
                                 (size_t)(b_base + prow) * Uu + u_base + usec * 2);
      __hip_atomic_store(hp, hpack, __ATOMIC_RELAXED, __HIP_MEMORY_SCOPE_AGENT);
    }
    __threadfence();
    __syncthreads();
    // ---- barrier arrive (group of 32 blocks) ----
    if (tid == 0) {
      unsigned old = __hip_atomic_fetch_add(cnt, 1u, __ATOMIC_ACQ_REL, __HIP_MEMORY_SCOPE_AGENT);
      if (old == 31u) {
        __hip_atomic_store(cnt, 0u, __ATOMIC_RELAXED, __HIP_MEMORY_SCOPE_AGENT);
        __hip_atomic_store(gen, (unsigned)(t + 1), __ATOMIC_RELEASE, __HIP_MEMORY_SCOPE_AGENT);
      }
    }

    // ---- y_{t-1} decode from LDS h copy (hides barrier latency) ----
    if (t > 0) {
      float s0 = 0.f, s1 = 0.f;
#pragma unroll
      for (int c8 = 0; c8 < 8; ++c8) {
        int k = 256 + usec * 64 + c8 * 8;
        bs8 hv = *(const bs8*)(zs + zbyte(prow, k));
#pragma unroll
        for (int e = 0; e < 8; ++e) {
          float hf = bf2f((unsigned short)hv[e]);
          int u = usec * 64 + c8 * 8 + e;
          const float* wdp = Wd + (size_t)u * Oo + oc0;
          s0 += hf * wdp[0];
          s1 += hf * wdp[1];
        }
      }
      ypart[prow][0][usec] = s0;
      ypart[prow][1][usec] = s1;
    }
    __syncthreads();
    if (t > 0 && tid < 64) {
      int b = tid >> 1, oc = tid & 1;
      float s = bd[oc0 + oc];
#pragma unroll
      for (int q = 0; q < 8; ++q) s += ypart[b][oc][q];
      out[((size_t)(b_base + b) * Tt + (t - 1)) * Oo + oc0 + oc] = s;
    }

    // ---- barrier wait ----
    if (tid == 0) {
      while (__hip_atomic_load(gen, __ATOMIC_ACQUIRE, __HIP_MEMORY_SCOPE_AGENT) <
             (unsigned)(t + 1)) {}
    }
    __syncthreads();
  }

  // ---- epilogue: y_{T-1} ----
  {
    const unsigned short* hsrc = hbuf + (size_t)((Tt - 1) & 1) * Bb * Uu;
#pragma unroll
    for (int i = 0; i < 8; ++i) {
      int c = tid + i * 256;
      int row = c >> 6;
      int u0 = (c & 63) * 8;
      const unsigned long long* p =
          (const unsigned long long*)(hsrc + (size_t)(b_base + row) * Uu + u0);
      U16 uu;
      uu.q[0] = __hip_atomic_load(p, __ATOMIC_RELAXED, __HIP_MEMORY_SCOPE_AGENT);
      uu.q[1] = __hip_atomic_load(p + 1, __ATOMIC_RELAXED, __HIP_MEMORY_SCOPE_AGENT);
      *(bs8*)(zs + zbyte(row, 256 + u0)) = uu.v;
    }
    __syncthreads();
    float s0 = 0.f, s1 = 0.f;
#pragma unroll
    for (int c8 = 0; c8 < 8; ++c8) {
      int k = 256 + usec * 64 + c8 * 8;
      bs8 hv = *(const bs8*)(zs + zbyte(prow, k));
#pragma unroll
      for (int e = 0; e < 8; ++e) {
        float hf = bf2f((unsigned short)hv[e]);
        int u = usec * 64 + c8 * 8 + e;
        const float* wdp = Wd + (size_t)u * Oo + oc0;
        s0 += hf * wdp[0];
        s1 += hf * wdp[1];
      }
    }
    ypart[prow][0][usec] = s0;
    ypart[prow][1][usec] = s1;
    __syncthreads();
    if (tid < 64) {
      int b = tid >> 1, oc = tid & 1;
      float s = bd[oc0 + oc];
#pragma unroll
      for (int q = 0; q < 8; ++q) s += ypart[b][oc][q];
      out[((size_t)(b_base + b) * Tt + (Tt - 1)) * Oo + oc0 + oc] = s;
    }
  }
}

extern "C" void kernel_launch(void* const* d_in, const int* in_sizes, int n_in,
                              void* d_out, int out_size, void* d_ws, size_t ws_size,
                              hipStream_t stream) {
  const float* x  = (const float*)d_in[0];
  const float* Wx = (const float*)d_in[1];
  const float* Wh = (const float*)d_in[2];
  const float* bs = (const float*)d_in[3];
  const float* Wd = (const float*)d_in[4];
  const float* bd = (const float*)d_in[5];
  float* out = (float*)d_out;

  unsigned short* hbuf = (unsigned short*)d_ws;                       // 2*256*512 bf16 = 512 KiB
  unsigned* bar = (unsigned*)((char*)d_ws + (size_t)2 * Bb * Uu * 2); // 8 groups * 32 uints

  rnn_init_bar<<<1, 256, 0, stream>>>(bar);
  rnn_lstm_kernel<<<dim3(256), dim3(256), 0, stream>>>(x, Wx, Wh, bs, Wd, bd, out, hbuf, bar);
}

// Round 3
// 5765.427 us; speedup vs baseline: 2.7216x; 2.7216x over previous
//
#include <hip/hip_runtime.h>

// LSTM surrogate: B=256, T=512, D=256, U=512, O=64.
// 8 batch-groups x 32 unit-groups = 256 blocks (1/CU), plain launch.
// R3: flag-based barrier, ALL cross-block ops relaxed agent (sc1, L3-homed):
// no acquire polls (buffer_inv/step killer), no threadfence, no RMW contention.
// x-staging and y-decode scheduled inside the barrier window.

#define Bb 256
#define Tt 512
#define Dd 256
#define Uu 512
#define Oo 64

typedef short bs8 __attribute__((ext_vector_type(8)));      // 8 bf16 (bits)
typedef float f32x16 __attribute__((ext_vector_type(16)));

__device__ __forceinline__ unsigned short f2bf(float f) {
  unsigned u = __float_as_uint(f);
  u += 0x7fffu + ((u >> 16) & 1u);                          // RNE
  return (unsigned short)(u >> 16);
}
__device__ __forceinline__ float bf2f(unsigned short s) {
  return __uint_as_float(((unsigned)s) << 16);
}
__device__ __forceinline__ float sigm(float v) { return 1.0f / (1.0f + __expf(-v)); }
__device__ __forceinline__ float tanhfast(float v) { return 2.0f / (1.0f + __expf(-2.0f * v)) - 1.0f; }

// z LDS: [32 rows][768 k] bf16, row stride 1536 B. XOR swizzle on 16B granules
// breaks the 32-way bank conflict of the stride-1536 column read (G4 / m214).
__device__ __forceinline__ int zbyte(int row, int k) {
  return (row * 1536 + k * 2) ^ ((row & 7) << 4);
}

__global__ void rnn_init_bar(unsigned* bar) {
  // agent-scope stores: visible at L3 to the main kernel's sc1 polls
  __hip_atomic_store(&bar[threadIdx.x], 0u, __ATOMIC_RELAXED, __HIP_MEMORY_SCOPE_AGENT);
}

__launch_bounds__(256, 1)
__global__ void rnn_lstm_kernel(const float* __restrict__ x, const float* __restrict__ Wx,
                                const float* __restrict__ Wh, const float* __restrict__ bias,
                                const float* __restrict__ Wd, const float* __restrict__ bd,
                                float* __restrict__ out, unsigned short* hbuf, unsigned* bar) {
  __shared__ __align__(16) char zs[32 * 768 * 2];   // 49152 B
  __shared__ float cpT[2][32][33];                  // partial C, [nt][col][row], +1 pad
  __shared__ float ypart[32][2][8];                 // y partial sums

  const int tid = threadIdx.x;
  const int lane = tid & 63;
  const int wid = tid >> 6;
  const int bid = blockIdx.x;
  const int bg = bid & 7;        // batch group 0..7 (XCD-affine perf heuristic only)
  const int ug = bid >> 3;       // unit group 0..31
  const int b_base = bg * 32;
  const int u_base = ug * 16;
  const int oc0 = ug * 2;
  const int kh = wid >> 1;       // K-half (0: k 0..383, 1: k 384..767)
  const int nt = wid & 1;        // N-tile (32 gate cols each)

  unsigned* fl = bar + bg * 32;  // 32 per-block flags, one 128B line per group

  // ---- load weight slice as B-fragments (once) ----
  // B-frag layout (32x32x16): col = lane&31, k = (lane>>5)*8 + e
  bs8 breg[24];
  {
    const int col = nt * 32 + (lane & 31);
    const int gate = col >> 4;                       // 0:i 1:f 2:g 3:o
    const int gc = gate * 512 + u_base + (col & 15); // global gate column
    const int kfr = (lane >> 5) * 8;
#pragma unroll
    for (int ks = 0; ks < 24; ++ks) {
      bs8 bb;
#pragma unroll
      for (int e = 0; e < 8; ++e) {
        int kg = kh * 384 + ks * 16 + kfr + e;
        float w = (kg < 256) ? Wx[(size_t)kg * 2048 + gc]
                             : Wh[(size_t)(kg - 256) * 2048 + gc];
        bb[e] = (short)f2bf(w);
      }
      breg[ks] = bb;
    }
  }

  // pointwise ownership: thread -> (prow = tid&31, usec = tid>>5), units usec*2+{0,1}
  const int prow = tid & 31;
  const int usec = tid >> 5;
  float bi[2], bff[2], bgg[2], boo[2];
#pragma unroll
  for (int j = 0; j < 2; ++j) {
    int ugl = u_base + usec * 2 + j;
    bi[j]  = bias[0 * 512 + ugl];
    bff[j] = bias[1 * 512 + ugl];
    bgg[j] = bias[2 * 512 + ugl];
    boo[j] = bias[3 * 512 + ugl];
  }
  float cst[2] = {0.f, 0.f};

  union U16 { unsigned long long q[2]; bs8 v; };

  // ---- prologue: stage x_0, zero h-region ----
#pragma unroll
  for (int i = 0; i < 4; ++i) {
    int c = tid + i * 256;
    int row = c >> 5;
    int d0 = (c & 31) * 8;
    const float* xp = x + ((size_t)(b_base + row) * Tt + 0) * Dd + d0;
    float4 v0 = *(const float4*)xp;
    float4 v1 = *(const float4*)(xp + 4);
    bs8 pk;
    pk[0] = (short)f2bf(v0.x); pk[1] = (short)f2bf(v0.y);
    pk[2] = (short)f2bf(v0.z); pk[3] = (short)f2bf(v0.w);
    pk[4] = (short)f2bf(v1.x); pk[5] = (short)f2bf(v1.y);
    pk[6] = (short)f2bf(v1.z); pk[7] = (short)f2bf(v1.w);
    *(bs8*)(zs + zbyte(row, d0)) = pk;
  }
#pragma unroll
  for (int i = 0; i < 8; ++i) {
    int c = tid + i * 256;
    int row = c >> 6;
    int u0 = (c & 63) * 8;
    bs8 zz = {0, 0, 0, 0, 0, 0, 0, 0};
    *(bs8*)(zs + zbyte(row, 256 + u0)) = zz;
  }
  __syncthreads();

  for (int t = 0; t < Tt; ++t) {
    // ---- gates MFMA: C[32 rows x 32 cols] per (kh, nt) wave ----
    f32x16 acc = {0, 0, 0, 0, 0, 0, 0, 0, 0, 0, 0, 0, 0, 0, 0, 0};
    {
      const int arow = lane & 31;
      const int akf = (lane >> 5) * 8;
#pragma unroll
      for (int ks = 0; ks < 24; ++ks) {
        int k = kh * 384 + ks * 16 + akf;
        bs8 av = *(const bs8*)(zs + zbyte(arow, k));
        acc = __builtin_amdgcn_mfma_f32_32x32x16_bf16(av, breg[ks], acc, 0, 0, 0);
      }
    }
    // ---- K-split combine: kh=1 writes partials, kh=0 adds ----
    // C/D layout (HW-verified): col = lane&31, row = (reg&3) + 8*(reg>>2) + 4*(lane>>5)
    {
      const int col = lane & 31;
      const int rb = 4 * (lane >> 5);
      if (kh == 1) {
#pragma unroll
        for (int q = 0; q < 4; ++q)
#pragma unroll
          for (int j = 0; j < 4; ++j)
            cpT[nt][col][8 * q + rb + j] = acc[4 * q + j];
      }
      __syncthreads();
      if (kh == 0) {
#pragma unroll
        for (int q = 0; q < 4; ++q)
#pragma unroll
          for (int j = 0; j < 4; ++j)
            cpT[nt][col][8 * q + rb + j] += acc[4 * q + j];
      }
      __syncthreads();
    }

    // ---- pointwise LSTM cell; h published bf16 (relaxed agent / sc1 -> L3) ----
    {
      unsigned hpack = 0;
#pragma unroll
      for (int j = 0; j < 2; ++j) {
        int u = usec * 2 + j;
        float gi = cpT[0][u][prow]      + bi[j];
        float gf = cpT[0][16 + u][prow] + bff[j];
        float gg = cpT[1][u][prow]      + bgg[j];
        float go = cpT[1][16 + u][prow] + boo[j];
        float iv = sigm(gi), fv = sigm(gf), gv = tanhfast(gg), ov = sigm(go);
        float cn = fv * cst[j] + iv * gv;
        cst[j] = cn;
        float hv = ov * tanhfast(cn);
        hpack |= ((unsigned)f2bf(hv)) << (16 * j);
      }
      unsigned* hp = (unsigned*)(hbuf + (size_t)(t & 1) * Bb * Uu +
                                 (size_t)(b_base + prow) * Uu + u_base + usec * 2);
      __hip_atomic_store(hp, hpack, __ATOMIC_RELAXED, __HIP_MEMORY_SCOPE_AGENT);
    }
    // __syncthreads drains each wave's vmcnt (sc1 store-ack => agent-visible),
    // so the flag store below is release-ordered without any L2 wb/inv.
    __syncthreads();
    if (tid == 0)
      __hip_atomic_store(&fl[ug], (unsigned)(t + 1), __ATOMIC_RELAXED, __HIP_MEMORY_SCOPE_AGENT);

    // ---- barrier window: stage x_{t+1} (x-region of zs is dead) ----
    if (t + 1 < Tt) {
#pragma unroll
      for (int i = 0; i < 4; ++i) {
        int c = tid + i * 256;
        int row = c >> 5;
        int d0 = (c & 31) * 8;
        const float* xp = x + ((size_t)(b_base + row) * Tt + (t + 1)) * Dd + d0;
        float4 v0 = *(const float4*)xp;
        float4 v1 = *(const float4*)(xp + 4);
        bs8 pk;
        pk[0] = (short)f2bf(v0.x); pk[1] = (short)f2bf(v0.y);
        pk[2] = (short)f2bf(v0.z); pk[3] = (short)f2bf(v0.w);
        pk[4] = (short)f2bf(v1.x); pk[5] = (short)f2bf(v1.y);
        pk[6] = (short)f2bf(v1.z); pk[7] = (short)f2bf(v1.w);
        *(bs8*)(zs + zbyte(row, d0)) = pk;
      }
    }

    // ---- barrier window: y_{t-1} decode from LDS h copy (h_{t-1} still staged) ----
    if (t > 0) {
      float s0 = 0.f, s1 = 0.f;
#pragma unroll
      for (int c8 = 0; c8 < 8; ++c8) {
        int k = 256 + usec * 64 + c8 * 8;
        bs8 hv = *(const bs8*)(zs + zbyte(prow, k));
#pragma unroll
        for (int e = 0; e < 8; ++e) {
          float hf = bf2f((unsigned short)hv[e]);
          int u = usec * 64 + c8 * 8 + e;
          const float* wdp = Wd + (size_t)u * Oo + oc0;
          s0 += hf * wdp[0];
          s1 += hf * wdp[1];
        }
      }
      ypart[prow][0][usec] = s0;
      ypart[prow][1][usec] = s1;
    }
    __syncthreads();
    if (t > 0 && tid < 64) {
      int b = tid >> 1, oc = tid & 1;
      float s = bd[oc0 + oc];
#pragma unroll
      for (int q = 0; q < 8; ++q) s += ypart[b][oc][q];
      out[((size_t)(b_base + b) * Tt + (t - 1)) * Oo + oc0 + oc] = s;
    }

    // ---- poll: wave0's 32 lanes read all 32 flags in one request, RELAXED ----
    if (wid == 0) {
      unsigned v;
      do {
        v = __hip_atomic_load(&fl[lane & 31], __ATOMIC_RELAXED, __HIP_MEMORY_SCOPE_AGENT);
      } while (__any((int)(v < (unsigned)(t + 1))));
    }
    __builtin_amdgcn_sched_barrier(0);
    __syncthreads();

    // ---- stage h_t from hbuf[t&1] (sc1 loads: L3-coherent, no stale L2/L1) ----
    {
      const unsigned short* hsrc = hbuf + (size_t)(t & 1) * Bb * Uu;
#pragma unroll
      for (int i = 0; i < 8; ++i) {
        int c = tid + i * 256;
        int row = c >> 6;
        int u0 = (c & 63) * 8;
        const unsigned long long* p =
            (const unsigned long long*)(hsrc + (size_t)(b_base + row) * Uu + u0);
        U16 uu;
        uu.q[0] = __hip_atomic_load(p, __ATOMIC_RELAXED, __HIP_MEMORY_SCOPE_AGENT);
        uu.q[1] = __hip_atomic_load(p + 1, __ATOMIC_RELAXED, __HIP_MEMORY_SCOPE_AGENT);
        *(bs8*)(zs + zbyte(row, 256 + u0)) = uu.v;
      }
    }
    __syncthreads();
  }

  // ---- epilogue: y_{T-1} (h_{T-1} already staged by final iteration) ----
  {
    float s0 = 0.f, s1 = 0.f;
#pragma unroll
    for (int c8 = 0; c8 < 8; ++c8) {
      int k = 256 + usec * 64 + c8 * 8;
      bs8 hv = *(const bs8*)(zs + zbyte(prow, k));
#pragma unroll
      for (int e = 0; e < 8; ++e) {
        float hf = bf2f((unsigned short)hv[e]);
        int u = usec * 64 + c8 * 8 + e;
        const float* wdp = Wd + (size_t)u * Oo + oc0;
        s0 += hf * wdp[0];
        s1 += hf * wdp[1];
      }
    }
    ypart[prow][0][usec] = s0;
    ypart[prow][1][usec] = s1;
    __syncthreads();
    if (tid < 64) {
      int b = tid >> 1, oc = tid & 1;
      float s = bd[oc0 + oc];
#pragma unroll
      for (int q = 0; q < 8; ++q) s += ypart[b][oc][q];
      out[((size_t)(b_base + b) * Tt + (Tt - 1)) * Oo + oc0 + oc] = s;
    }
  }
}

extern "C" void kernel_launch(void* const* d_in, const int* in_sizes, int n_in,
                              void* d_out, int out_size, void* d_ws, size_t ws_size,
                              hipStream_t stream) {
  const float* x  = (const float*)d_in[0];
  const float* Wx = (const float*)d_in[1];
  const float* Wh = (const float*)d_in[2];
  const float* bs = (const float*)d_in[3];
  const float* Wd = (const float*)d_in[4];
  const float* bd = (const float*)d_in[5];
  float* out = (float*)d_out;

  unsigned short* hbuf = (unsigned short*)d_ws;                       // 2*256*512 bf16 = 512 KiB
  unsigned* bar = (unsigned*)((char*)d_ws + (size_t)2 * Bb * Uu * 2); // 8 groups * 32 flags

  rnn_init_bar<<<1, 256, 0, stream>>>(bar);
  rnn_lstm_kernel<<<dim3(256), dim3(256), 0, stream>>>(x, Wx, Wh, bs, Wd, bd, out, hbuf, bar);
}